// Round 3
// baseline (370.977 us; speedup 1.0000x reference)
//
#include <hip/hip_runtime.h>

// QuantileLoss: scalar = ( sum_rows[ (p0-t0)^2+(p1-t1)^2+(p2-t2)^2 + 2*lower ] ) / (5N)
// lower = p3>p2 ? 1000 : (p3 > 0.95*t2 ? 0 : (p3-0.95*t2)^2)
//
// R1: row-structured loads (bad lane stride)      -> 101 us, 16% HBM peak
// R2: LDS-staged, perfectly coalesced             -> 105 us, identical. Coalescing is NOT the limiter.
// Common factor: 268 MB footprint vs 256 MB L3, ~50% L3 hit (FETCH=134MB), 2.55 TB/s effective.
// R3 theory: mixed L3-hit/miss stream is the pathology. Use nontemporal loads (nt policy,
// stream-once data) to go straight to HBM; max MLP (16 float4 loads hoisted per thread);
// simple no-LDS structure; 4096 blocks, exactly 2 row-groups per thread.

#define NROWS 8388608                 // 2^23
#define NGROUPS (NROWS / 4)           // 2,097,152 groups of 4 rows
#define BLOCK 256
#define GRID 4096                     // 4096*256 threads * 2 groups = NGROUPS exactly

typedef float v4f __attribute__((ext_vector_type(4)));

__global__ void __launch_bounds__(256) qloss_partial(
    const float* __restrict__ preds,
    const float* __restrict__ target,
    double* __restrict__ ws)
{
    const int gid = blockIdx.x * BLOCK + threadIdx.x;   // 0 .. 1,048,575

    // Thread handles 8 contiguous rows: 160 B of preds (10 x float4),
    // 96 B of target (6 x float4). All 16B-aligned.
    const v4f* gp = (const v4f*)(preds + (size_t)gid * 40);
    const v4f* gt = (const v4f*)(target + (size_t)gid * 24);

    v4f p[10], t[6];
    #pragma unroll
    for (int k = 0; k < 10; ++k) p[k] = __builtin_nontemporal_load(gp + k);
    #pragma unroll
    for (int k = 0; k < 6; ++k)  t[k] = __builtin_nontemporal_load(gt + k);

    const float* pf = (const float*)p;
    const float* tf = (const float*)t;

    double acc = 0.0;
    float sum = 0.0f;
    #pragma unroll
    for (int r = 0; r < 8; ++r) {
        const float p0 = pf[5*r + 0];
        const float p1 = pf[5*r + 1];
        const float p2 = pf[5*r + 2];
        const float p3 = pf[5*r + 3];
        const float t0 = tf[3*r + 0];
        const float t1 = tf[3*r + 1];
        const float t2 = tf[3*r + 2];

        const float a0 = p0 - t0;
        const float a1 = p1 - t1;
        const float a2 = p2 - t2;
        const float m  = a0*a0 + a1*a1 + a2*a2;

        const float q = t2 * 0.95f;
        const float d = p3 - q;
        const float lower = (p3 > p2) ? 1000.0f : ((p3 > q) ? 0.0f : d * d);

        sum += m + 2.0f * lower;
        if (r == 3) { acc += (double)sum; sum = 0.0f; }  // 4-row float partials, as R1 (absmax was 0.0)
    }
    acc += (double)sum;

    // wave64 shuffle reduce
    #pragma unroll
    for (int off = 32; off > 0; off >>= 1)
        acc += __shfl_down(acc, off, 64);

    __shared__ double red[4];
    const int lane = threadIdx.x & 63;
    const int wave = threadIdx.x >> 6;
    if (lane == 0) red[wave] = acc;
    __syncthreads();

    if (threadIdx.x == 0)
        atomicAdd(ws, red[0] + red[1] + red[2] + red[3]);   // 4096 atomics total
}

__global__ void qloss_final(const double* __restrict__ ws, float* __restrict__ out)
{
    *out = (float)(*ws / (5.0 * (double)NROWS));
}

extern "C" void kernel_launch(void* const* d_in, const int* in_sizes, int n_in,
                              void* d_out, int out_size, void* d_ws, size_t ws_size,
                              hipStream_t stream)
{
    const float* preds  = (const float*)d_in[0];
    const float* target = (const float*)d_in[1];
    float* out  = (float*)d_out;
    double* ws  = (double*)d_ws;

    // d_ws is re-poisoned to 0xAA before every timed launch — zero the accumulator.
    hipMemsetAsync(ws, 0, sizeof(double), stream);

    qloss_partial<<<GRID, BLOCK, 0, stream>>>(preds, target, ws);
    qloss_final<<<1, 1, 0, stream>>>(ws, out);
}

// Round 4
// 279.501 us; speedup vs baseline: 1.3273x; 1.3273x over previous
//
#include <hip/hip_runtime.h>

// QuantileLoss: scalar = ( sum_rows[ (p0-t0)^2+(p1-t1)^2+(p2-t2)^2 + 2*lower ] ) / (5N)
// lower = p3>p2 ? 1000 : (p3 > 0.95*t2 ? 0 : (p3-0.95*t2)^2)
//
// R1 (row loads, no LDS):        101 us kernel, pins 1.36 TB/s, FETCH 134 MB (L3 serves half)
// R2 (LDS staged, coalesced):    105 us, identical -> coalescing not the limiter
// R3 (NT, 160B/thread chunks):   150 us, pins 2.68 TB/s (NT doubles pin rate!) but 1.46x
//                                over-fetch (NT drops lines between the 8 touches/line)
// R4: NT + lane-contiguous staging (1 wave instr = 8 full 128B lines consumed once,
//     no over-fetch) + LDS reassembly + 2-stage pipeline (next chunk's loads in
//     flight during current compute).

#define NROWS 8388608                      // 2^23
#define ROWS_PER_CHUNK 1024
#define NCHUNKS (NROWS / ROWS_PER_CHUNK)   // 8192
#define PCHUNK (ROWS_PER_CHUNK * 5)        // 5120 floats = 20 KB
#define TCHUNK (ROWS_PER_CHUNK * 3)        // 3072 floats = 12 KB
#define GRID 2048
#define CHUNKS_PER_BLOCK (NCHUNKS / GRID)  // 4

typedef float v4f __attribute__((ext_vector_type(4)));

__global__ void __launch_bounds__(256) qloss_partial(
    const float* __restrict__ preds,
    const float* __restrict__ target,
    double* __restrict__ ws)
{
    __shared__ float sp[PCHUNK];
    __shared__ float st[TCHUNK];

    const int t = threadIdx.x;
    double acc = 0.0;

    // Prologue: load chunk 0 for this block.
    v4f rp[5], rt[3];
    {
        const v4f* gp = (const v4f*)(preds + (size_t)blockIdx.x * PCHUNK);
        const v4f* gt = (const v4f*)(target + (size_t)blockIdx.x * TCHUNK);
        #pragma unroll
        for (int k = 0; k < 5; ++k) rp[k] = __builtin_nontemporal_load(gp + t + k * 256);
        #pragma unroll
        for (int k = 0; k < 3; ++k) rt[k] = __builtin_nontemporal_load(gt + t + k * 256);
    }

    #pragma unroll
    for (int i = 0; i < CHUNKS_PER_BLOCK; ++i) {
        // Stage current chunk into LDS.
        #pragma unroll
        for (int k = 0; k < 5; ++k) ((v4f*)sp)[t + k * 256] = rp[k];
        #pragma unroll
        for (int k = 0; k < 3; ++k) ((v4f*)st)[t + k * 256] = rt[k];
        __syncthreads();

        // Kick off next chunk's NT loads; they stay in flight during compute.
        if (i + 1 < CHUNKS_PER_BLOCK) {
            const int nc = blockIdx.x + (i + 1) * GRID;
            const v4f* gp = (const v4f*)(preds + (size_t)nc * PCHUNK);
            const v4f* gt = (const v4f*)(target + (size_t)nc * TCHUNK);
            #pragma unroll
            for (int k = 0; k < 5; ++k) rp[k] = __builtin_nontemporal_load(gp + t + k * 256);
            #pragma unroll
            for (int k = 0; k < 3; ++k) rt[k] = __builtin_nontemporal_load(gt + t + k * 256);
        }

        // Compute 4 rows/thread out of LDS (stride 5/3: 2-way bank alias, free).
        float sum = 0.0f;
        #pragma unroll
        for (int rr = 0; rr < 4; ++rr) {
            const int r = t + rr * 256;
            const float p0 = sp[5*r + 0];
            const float p1 = sp[5*r + 1];
            const float p2 = sp[5*r + 2];
            const float p3 = sp[5*r + 3];
            const float t0 = st[3*r + 0];
            const float t1 = st[3*r + 1];
            const float t2 = st[3*r + 2];

            const float a0 = p0 - t0;
            const float a1 = p1 - t1;
            const float a2 = p2 - t2;
            const float m  = a0*a0 + a1*a1 + a2*a2;

            const float q = t2 * 0.95f;
            const float d = p3 - q;
            const float lower = (p3 > p2) ? 1000.0f : ((p3 > q) ? 0.0f : d * d);

            sum += m + 2.0f * lower;
        }
        acc += (double)sum;
        __syncthreads();   // LDS safe to overwrite next iteration
    }

    // wave64 shuffle reduce
    #pragma unroll
    for (int off = 32; off > 0; off >>= 1)
        acc += __shfl_down(acc, off, 64);

    __shared__ double red[4];
    const int lane = t & 63;
    const int wave = t >> 6;
    if (lane == 0) red[wave] = acc;
    __syncthreads();

    if (t == 0)
        atomicAdd(ws, red[0] + red[1] + red[2] + red[3]);   // 2048 atomics total

}

__global__ void qloss_final(const double* __restrict__ ws, float* __restrict__ out)
{
    *out = (float)(*ws / (5.0 * (double)NROWS));
}

extern "C" void kernel_launch(void* const* d_in, const int* in_sizes, int n_in,
                              void* d_out, int out_size, void* d_ws, size_t ws_size,
                              hipStream_t stream)
{
    const float* preds  = (const float*)d_in[0];
    const float* target = (const float*)d_in[1];
    float* out  = (float*)d_out;
    double* ws  = (double*)d_ws;

    // d_ws is re-poisoned to 0xAA before every timed launch — zero the accumulator.
    hipMemsetAsync(ws, 0, sizeof(double), stream);

    qloss_partial<<<GRID, 256, 0, stream>>>(preds, target, ws);
    qloss_final<<<1, 1, 0, stream>>>(ws, out);
}